// Round 1
// baseline (23694.281 us; speedup 1.0000x reference)
//
#include <hip/hip_runtime.h>
#include <math.h>

#define B   16
#define H   512
#define G4  2048      // 4*H gate rows per layer
#define V   32000
#define T   300
#define NBLK 256
#define VPB  125      // vocab rows per block (V / NBLK)
#define LSTR 516      // LDS row stride (pad 512 -> 516: 2-way bank aliasing only, free)

// ws layout (float offsets):
//  h0[2] : 0      (2 * 8192)
//  h1[2] : 16384  (2 * 8192)
//  c0    : 32768  (8192)
//  c1    : 40960  (8192)
//  pval  : 49152  (256*16 floats)
//  pidx  : 53248  (256*16 ints)
#define WS_H0   0
#define WS_H1   16384
#define WS_C0   32768
#define WS_C1   40960
#define WS_PVAL 49152
#define WS_PIDX 53248
#define WS_FLOATS 57344

__device__ __forceinline__ float sigf(float v) { return 1.0f / (1.0f + expf(-v)); }

// One LSTM layer. Grid = 256 blocks, block = 256 threads.
// Block bid owns hidden dims d in {2*bid, 2*bid+1} -> gate rows 512*g + d.
// layer==0: input = (t==0 ? x : W_tied[idx]) where idx is reduced from K3(t-1) partials.
// layer==1: input = h0_new (buffer wb).
__global__ __launch_bounds__(256) void lstm_kernel(
    const float* __restrict__ x,  const float* __restrict__ Wt,
    const float* __restrict__ Wih, const float* __restrict__ Whh,
    const float* __restrict__ bih, const float* __restrict__ bhh,
    float* __restrict__ ws, int t, int layer)
{
    __shared__ __align__(16) float e_lds[B * LSTR];
    __shared__ __align__(16) float h_lds[B * LSTR];
    __shared__ float partial[256];
    __shared__ float gate_lds[B * 8];
    __shared__ float rv[256];
    __shared__ int   ri[256];
    __shared__ int   idx_lds[B];

    const int tid = threadIdx.x;
    const int bid = blockIdx.x;
    const int rb = t & 1, wb = rb ^ 1;

    float* pval = ws + WS_PVAL;
    int*   pidx = (int*)(ws + WS_PIDX);

    const float* hsrc; float* cptr; float* hout;
    const float* Wa; const float* Wb_; const float* bi; const float* bh;
    if (layer == 0) {
        hsrc = ws + WS_H0 + rb * 8192; cptr = ws + WS_C0; hout = ws + WS_H0 + wb * 8192;
        Wa = Wih; Wb_ = Whh; bi = bih; bh = bhh;
    } else {
        hsrc = ws + WS_H1 + rb * 8192; cptr = ws + WS_C1; hout = ws + WS_H1 + wb * 8192;
        Wa = Wih + G4 * H; Wb_ = Whh + G4 * H; bi = bih + G4; bh = bhh + G4;
    }

    // ---- Phase A: redundant 256-partial argmax reduce (layer 0, t > 0) ----
    if (layer == 0 && t > 0) {
        {
            int b = tid & 15, ch = tid >> 4;
            float bv = -1e30f; int bidx = 0x7fffffff;
            for (int j = 0; j < 16; ++j) {
                int blk = ch * 16 + j;
                float v = pval[blk * 16 + b];
                int   i = pidx[blk * 16 + b];
                if (v > bv || (v == bv && i < bidx)) { bv = v; bidx = i; }
            }
            rv[ch * 16 + b] = bv; ri[ch * 16 + b] = bidx;
        }
        __syncthreads();
        if (tid < 16) {
            int b = tid; float bv = -1e30f; int bidx = 0x7fffffff;
            for (int ch = 0; ch < 16; ++ch) {
                float v = rv[ch * 16 + b]; int i = ri[ch * 16 + b];
                if (v > bv || (v == bv && i < bidx)) { bv = v; bidx = i; }
            }
            idx_lds[b] = bidx;
        }
        __syncthreads();
    }

    // ---- Stage e (input) and h (recurrent state) into LDS, coalesced float4 ----
    for (int i = 0; i < 8; ++i) {
        int j = tid + 256 * i;            // 2048 float4 total
        int b = j >> 7, k4 = (j & 127) << 2;
        const float4* esrc;
        if (layer == 0) {
            esrc = (t == 0) ? (const float4*)(x + b * H + k4)
                            : (const float4*)(Wt + (long)idx_lds[b] * H + k4);
        } else {
            esrc = (const float4*)(ws + WS_H0 + wb * 8192 + b * H + k4);
        }
        float4 ev = *esrc;
        *(float4*)&e_lds[b * LSTR + k4] = ev;
        float4 hv = *(const float4*)(hsrc + b * H + k4);
        *(float4*)&h_lds[b * LSTR + k4] = hv;
    }
    __syncthreads();

    // ---- Gate dot products: thread = (b, gate, dim-half, k-split) ----
    {
        int b = tid & 15, g = (tid >> 4) & 3, dh = (tid >> 6) & 1, ks = tid >> 7;
        int row = (g << 9) + bid * 2 + dh;
        const float* wa = Wa  + (long)row * H;
        const float* wb2 = Wb_ + (long)row * H;
        const float* ep = &e_lds[b * LSTR];
        const float* hp = &h_lds[b * LSTR];
        float acc = 0.0f;
        int k0 = ks * 256;
        #pragma unroll 8
        for (int k = k0; k < k0 + 256; k += 4) {
            float4 w1 = *(const float4*)(wa + k);
            float4 e1 = *(const float4*)(ep + k);
            acc += w1.x * e1.x + w1.y * e1.y + w1.z * e1.z + w1.w * e1.w;
            float4 w2 = *(const float4*)(wb2 + k);
            float4 h1 = *(const float4*)(hp + k);
            acc += w2.x * h1.x + w2.y * h1.y + w2.z * h1.z + w2.w * h1.w;
        }
        partial[tid] = acc;
    }
    __syncthreads();
    if (tid < 128) {
        int b = tid & 15, g = (tid >> 4) & 3, dh = (tid >> 6) & 1;
        int row = (g << 9) + bid * 2 + dh;
        float s = partial[tid] + partial[tid + 128] + bi[row] + bh[row];
        gate_lds[b * 8 + dh * 4 + g] = s;
    }
    __syncthreads();
    if (tid < 32) {
        int b = tid & 15, dh = tid >> 4;
        int d = bid * 2 + dh;
        float gi = gate_lds[b * 8 + dh * 4 + 0];
        float gf = gate_lds[b * 8 + dh * 4 + 1];
        float gg = gate_lds[b * 8 + dh * 4 + 2];
        float go = gate_lds[b * 8 + dh * 4 + 3];
        float co = cptr[b * H + d];
        float cn = sigf(gf) * co + sigf(gi) * tanhf(gg);
        float hn = sigf(go) * tanhf(cn);
        cptr[b * H + d] = cn;
        hout[b * H + d] = hn;
    }
}

// Logits + per-block partial argmax. Grid = 256 blocks x 512 threads.
// Block bid owns vocab rows [bid*125, bid*125+125). Thread = (tb = batch, tv),
// rows v = vbase + tv + 32*m, m = 0..3 (m==3 valid only for tv < 29).
__global__ __launch_bounds__(512) void logits_kernel(
    const float* __restrict__ Wt, const float* __restrict__ bpred,
    float* __restrict__ ws, float* __restrict__ out, int t)
{
    __shared__ __align__(16) float h_lds[B * LSTR];
    __shared__ float red_v[512];
    __shared__ int   red_i[512];

    const int tid = threadIdx.x, bid = blockIdx.x;
    const int wb = (t & 1) ^ 1;
    const float* h1 = ws + WS_H1 + wb * 8192;

    for (int i = 0; i < 4; ++i) {
        int j = tid + 512 * i;            // 2048 float4
        int b = j >> 7, k4 = (j & 127) << 2;
        *(float4*)&h_lds[b * LSTR + k4] = *(const float4*)(h1 + b * H + k4);
    }
    __syncthreads();

    const int tb = tid & 15, tv = tid >> 4;
    const int vbase = bid * VPB;
    const int v0 = vbase + tv;
    const bool val3 = (tv + 96) < VPB;    // tv < 29
    const float* w0 = Wt + (long)v0 * H;
    const long off3 = val3 ? (long)96 * H : 0;   // clamp invalid row to dup of row v0
    const float* hp = &h_lds[tb * LSTR];

    float acc0 = 0.f, acc1 = 0.f, acc2 = 0.f, acc3 = 0.f;
    #pragma unroll 4
    for (int k = 0; k < H; k += 4) {
        float4 hv = *(const float4*)(hp + k);
        float4 a = *(const float4*)(w0 + k);
        acc0 += a.x * hv.x + a.y * hv.y + a.z * hv.z + a.w * hv.w;
        float4 b2 = *(const float4*)(w0 + 32 * H + k);
        acc1 += b2.x * hv.x + b2.y * hv.y + b2.z * hv.z + b2.w * hv.w;
        float4 c2 = *(const float4*)(w0 + 64 * H + k);
        acc2 += c2.x * hv.x + c2.y * hv.y + c2.z * hv.z + c2.w * hv.w;
        float4 d2 = *(const float4*)(w0 + off3 + k);
        acc3 += d2.x * hv.x + d2.y * hv.y + d2.z * hv.z + d2.w * hv.w;
    }

    const long obase = ((long)tb * T + t) * (long)V;
    float l0 = acc0 + bpred[v0];
    float l1 = acc1 + bpred[v0 + 32];
    float l2 = acc2 + bpred[v0 + 64];
    out[obase + v0]      = l0;
    out[obase + v0 + 32] = l1;
    out[obase + v0 + 64] = l2;
    float bv = l0; int bidx = v0;
    if (l1 > bv) { bv = l1; bidx = v0 + 32; }
    if (l2 > bv) { bv = l2; bidx = v0 + 64; }
    if (val3) {
        float l3 = acc3 + bpred[v0 + 96];
        out[obase + v0 + 96] = l3;
        if (l3 > bv) { bv = l3; bidx = v0 + 96; }
    }
    red_v[tid] = bv; red_i[tid] = bidx;
    __syncthreads();
    if (tid < 16) {
        int b = tid; float bbv = -1e30f; int bbi = 0x7fffffff;
        for (int q = 0; q < 32; ++q) {
            float v = red_v[q * 16 + b]; int i = red_i[q * 16 + b];
            if (v > bbv || (v == bbv && i < bbi)) { bbv = v; bbi = i; }
        }
        float* pval = ws + WS_PVAL;
        int*   pidx = (int*)(ws + WS_PIDX);
        pval[bid * 16 + b] = bbv;
        pidx[bid * 16 + b] = bbi;
    }
}

extern "C" void kernel_launch(void* const* d_in, const int* in_sizes, int n_in,
                              void* d_out, int out_size, void* d_ws, size_t ws_size,
                              hipStream_t stream) {
    const float* x   = (const float*)d_in[0];
    const float* Wt  = (const float*)d_in[1];
    const float* bp  = (const float*)d_in[2];
    const float* Wih = (const float*)d_in[3];
    const float* Whh = (const float*)d_in[4];
    const float* bih = (const float*)d_in[5];
    const float* bhh = (const float*)d_in[6];
    float* out = (float*)d_out;
    float* ws  = (float*)d_ws;

    // Zero LSTM state (h,c) and argmax partial buffers every call (ws is re-poisoned).
    hipMemsetAsync(d_ws, 0, (size_t)WS_FLOATS * sizeof(float), stream);

    for (int t = 0; t < T; ++t) {
        lstm_kernel<<<NBLK, 256, 0, stream>>>(x, Wt, Wih, Whh, bih, bhh, ws, t, 0);
        lstm_kernel<<<NBLK, 256, 0, stream>>>(x, Wt, Wih, Whh, bih, bhh, ws, t, 1);
        logits_kernel<<<NBLK, 512, 0, stream>>>(Wt, bp, ws, out, t);
    }
}